// Round 25
// baseline (264.623 us; speedup 1.0000x reference)
//
#include <hip/hip_runtime.h>
#include <math.h>

#define SS 4096
#define EE 1024
#define HH 16
#define DD 64
#define RMAX 128
#define NCOL 128
#define NRED 8
#define NPROJ 384  // 384 blocks * 8 e = 3072 outputs; W in registers, full K
#define NBG 64
#define NVS 16
#define NATT 256

// ---------------------------------------------------------------------------
// ws float offsets. LESSONS: (r9/r10) no 4KB-strided ws reads; (r3) no BULK
// global atomics; (r5/r7) no software grid barriers; (r13) no shallow-flight
// staging; (r19) not W-volume-bound; (r20) same-line lockstep contention is
// real (stagger!); (r21) not ILP-depth-bound; (r22-r24) e-split/LDS-W/both-LDS
// all ~33us: ds_read_b128=12cy makes ANY LDS-fed fp32 GEMM LDS-issue-bound at
// ~35us for 0.8GF. (r25) W STATIONARY IN REGISTERS (8 float4/lane), x via
// per-lane VMEM from L2, shfl-reduce over 32 k-slices: no LDS/scalar/broadcast
// in the hot loop; writes qh/kTh/vh directly (d1b dispatch eliminated).
//   meta   int[0..1]      (s0, L)
//   sumx   [EE]           @64
//   bgA    [EE]           @1088
//   betap  [HH][DD]       @2112   (atomic; zeroed by D1 block 0)
//   alphap [HH]           @3136
//   vsumh  [HH][DD]       @3200
//   partT  [EE][NCOL]     @8192
//   qh     [HH][RMAX][DD] @270336 (rows L..Lp-1 zeroed; >=Lp never read)
//   kTh    [HH][DD][RMAX] @401408 (cols L..Lp-1 zeroed; >=Lp masked in d2)
//   vh     [HH][RMAX][DD] @532480 (rows L..Lp-1 zeroed)
// ---------------------------------------------------------------------------
#define OFF_SUMX  64
#define OFF_BGA   1088
#define OFF_BETA  2112
#define OFF_ALPHA 3136
#define OFF_VSUM  3200
#define OFF_PART  8192
#define OFF_QH    270336
#define OFF_KTH   (OFF_QH + HH * RMAX * DD)
#define OFF_VH    (OFF_KTH + HH * DD * RMAX)

__device__ __forceinline__ void seg_scan(const int* __restrict__ seg,
                                         const int* __restrict__ posp,
                                         int* sh, int& s0, int& L) {
    if (threadIdx.x == 0) { sh[0] = SS; sh[1] = -1; }
    __syncthreads();
    int sid = seg[posp[0]];
    int lmin = SS, lmax = -1;
    for (int i = threadIdx.x; i < SS; i += 256)
        if (seg[i] == sid) { lmin = min(lmin, i); lmax = max(lmax, i); }
#pragma unroll
    for (int off = 32; off; off >>= 1) {
        lmin = min(lmin, __shfl_xor(lmin, off));
        lmax = max(lmax, __shfl_xor(lmax, off));
    }
    if ((threadIdx.x & 63) == 0) { atomicMin(&sh[0], lmin); atomicMax(&sh[1], lmax); }
    __syncthreads();
    s0 = sh[0];
    L  = sh[1] - sh[0] + 1;
    if (L > RMAX) L = RMAX;
    if (L < 1)    L = 1;
}

// -------- D0: colsum -> partT (128 blk) || seg scan -> meta (1 blk) --------
__global__ __launch_bounds__(256) void d0_kernel(
    const float* __restrict__ x, const int* __restrict__ seg,
    const int* __restrict__ posp, float* __restrict__ ws) {
    int bid = blockIdx.x, tid = threadIdx.x;
    if (bid < NCOL) {
        float* partT = ws + OFF_PART;
        int r0 = bid * (SS / NCOL);
        const float4* x4 = (const float4*)x;
        float4 a = make_float4(0.f, 0.f, 0.f, 0.f);
#pragma unroll 8
        for (int r = 0; r < SS / NCOL; ++r) {
            float4 v = x4[(size_t)(r0 + r) * 256 + tid];
            a.x += v.x; a.y += v.y; a.z += v.z; a.w += v.w;
        }
        partT[(size_t)(4 * tid + 0) * NCOL + bid] = a.x;
        partT[(size_t)(4 * tid + 1) * NCOL + bid] = a.y;
        partT[(size_t)(4 * tid + 2) * NCOL + bid] = a.z;
        partT[(size_t)(4 * tid + 3) * NCOL + bid] = a.w;
        return;
    }
    __shared__ int sh[2];
    int s0, L;
    seg_scan(seg, posp, sh, s0, L);
    if (tid == 0) { ((int*)ws)[0] = s0; ((int*)ws)[1] = L; }
}

// -------- D1: sumx reduce + zero accum (8 blk) || QKV proj (384 blk) --------
// Proj: lane = (e2 = lane>>5, kg = lane&31). Lane's W slice W[em][kg*32..+32)
// lives in 8 float4 REGISTERS (loaded once, coalesced). Per row r: 8 per-lane
// VMEM float4 x-reads + 32 FMA + 5-shfl reduce over kg; lanes 0/32 store the
// two e-results directly to qh/kTh/vh (bias + r<L gate applied here).
// Per-block r-start stagger breaks same-line lockstep (r20).
__global__ __launch_bounds__(256) void d1_kernel(
    const float* __restrict__ x,
    const float* __restrict__ Wq, const float* __restrict__ bq,
    const float* __restrict__ Wk, const float* __restrict__ bk,
    const float* __restrict__ Wv, const float* __restrict__ bv,
    float* __restrict__ ws) {
    int bid = blockIdx.x, tid = threadIdx.x;
    if (bid < NRED) {
        if (bid == 0) {   // zero betap+alphap atomic accumulators
            for (int i = tid; i < 1088; i += 256) (ws + OFF_BETA)[i] = 0.f;
        }
        const float* partT = ws + OFF_PART;
        int e  = bid * 128 + (tid >> 1);
        int c0 = (tid & 1) * 64;
        const float4* p4 = (const float4*)(partT + (size_t)e * NCOL + c0);
        float4 s4 = make_float4(0.f, 0.f, 0.f, 0.f);
#pragma unroll
        for (int i = 0; i < 16; ++i) {
            float4 v = p4[i];
            s4.x += v.x; s4.y += v.y; s4.z += v.z; s4.w += v.w;
        }
        float s = s4.x + s4.y + s4.z + s4.w;
        s += __shfl_xor(s, 1);
        if ((tid & 1) == 0) (ws + OFF_SUMX)[e] = s;
        return;
    }
    int s0 = ((const int*)ws)[0];
    int L  = ((const int*)ws)[1];
    int Lp = (L + 63) & ~63;
    int pid  = bid - NRED;            // 0..383
    int lane = tid & 63;
    int w4   = tid >> 6;
    int e2   = lane >> 5;             // 0/1
    int kg   = lane & 31;             // 32-k slice index
    int ge   = pid * 8 + w4 * 2 + e2; // global output column, 0..3071
    int m    = ge >> 10;
    int em   = ge & 1023;
    const float* Wm = (m == 0) ? Wq : ((m == 1) ? Wk : Wv);
    const float* bm = (m == 0) ? bq : ((m == 1) ? bk : bv);
    float bias = bm[em];
    const float4* wp = (const float4*)(Wm + (size_t)em * EE + kg * 32);
    float4 w0 = wp[0], w1 = wp[1], w2 = wp[2], w3 = wp[3];
    float4 w4v = wp[4], w5 = wp[5], w6 = wp[6], w7 = wp[7];
    int h = em >> 6, d = em & 63;
    float* qh  = ws + OFF_QH;
    float* kTh = ws + OFF_KTH;
    float* vh  = ws + OFF_VH;
    int r0off = pid & (Lp - 1);       // per-block row-phase stagger

#define LOADX(A0,A1,A2,A3,A4,A5,A6,A7, RR)                                   \
    {                                                                         \
        int r_  = (r0off + (RR)) & (Lp - 1);                                  \
        int rx_ = (r_ < L) ? (s0 + r_) : s0;                                  \
        const float4* xp_ = (const float4*)(x + (size_t)rx_ * EE + kg * 32);  \
        A0 = xp_[0]; A1 = xp_[1]; A2 = xp_[2]; A3 = xp_[3];                   \
        A4 = xp_[4]; A5 = xp_[5]; A6 = xp_[6]; A7 = xp_[7];                   \
    }
#define BODY(A0,A1,A2,A3,A4,A5,A6,A7, RR)                                    \
    {                                                                         \
        float t = A0.x * w0.x + A0.y * w0.y + A0.z * w0.z + A0.w * w0.w;      \
        t += A1.x * w1.x + A1.y * w1.y + A1.z * w1.z + A1.w * w1.w;           \
        t += A2.x * w2.x + A2.y * w2.y + A2.z * w2.z + A2.w * w2.w;           \
        t += A3.x * w3.x + A3.y * w3.y + A3.z * w3.z + A3.w * w3.w;           \
        t += A4.x * w4v.x + A4.y * w4v.y + A4.z * w4v.z + A4.w * w4v.w;       \
        t += A5.x * w5.x + A5.y * w5.y + A5.z * w5.z + A5.w * w5.w;           \
        t += A6.x * w6.x + A6.y * w6.y + A6.z * w6.z + A6.w * w6.w;           \
        t += A7.x * w7.x + A7.y * w7.y + A7.z * w7.z + A7.w * w7.w;           \
        t += __shfl_xor(t, 16);                                               \
        t += __shfl_xor(t, 8);                                                \
        t += __shfl_xor(t, 4);                                                \
        t += __shfl_xor(t, 2);                                                \
        t += __shfl_xor(t, 1);                                                \
        if (kg == 0) {                                                        \
            int r_ = (r0off + (RR)) & (Lp - 1);                               \
            float v_ = (r_ < L) ? (t + bias) : 0.f;                           \
            if (m == 1) kTh[(size_t)(h * DD + d) * RMAX + r_] = v_;           \
            else ((m == 0) ? qh : vh)[((size_t)h * RMAX + r_) * DD + d] = v_; \
        }                                                                     \
    }

    float4 a0, a1, a2, a3, a4, a5, a6, a7;
    float4 b0, b1, b2, b3, b4, b5, b6, b7;
    LOADX(a0,a1,a2,a3,a4,a5,a6,a7, 0)
    for (int rr = 0; rr < Lp; rr += 2) {
        LOADX(b0,b1,b2,b3,b4,b5,b6,b7, rr + 1)
        BODY(a0,a1,a2,a3,a4,a5,a6,a7, rr)
        LOADX(a0,a1,a2,a3,a4,a5,a6,a7, rr + 2)   // wraps on last iter (cheap)
        BODY(b0,b1,b2,b3,b4,b5,b6,b7, rr + 1)
    }
#undef LOADX
#undef BODY
}

// -------- D2: bgA (64) || vsumh (16) || attention, 1 wave per (r,h) (256) ----
__global__ __launch_bounds__(256) void d2_kernel(
    const float* __restrict__ Wv, const float* __restrict__ bv,
    float* __restrict__ ws) {
    __shared__ float qS[4 * 64];
    __shared__ float wS[4 * 128];
    __shared__ float vp_[4][64];
    const float* sumx = ws + OFF_SUMX;
    float* bgA    = ws + OFF_BGA;
    float* betap  = ws + OFF_BETA;
    float* alphap = ws + OFF_ALPHA;
    float* vsumh  = ws + OFF_VSUM;
    const float* qh  = ws + OFF_QH;
    const float* kTh = ws + OFF_KTH;
    const float* vh  = ws + OFF_VH;

    int bid = blockIdx.x, tid = threadIdx.x;
    int lane = tid & 63, wave = tid >> 6;
    int L  = ((const int*)ws)[1];
    int Lp = (L + 63) & ~63;

    if (bid < NBG) {
        int e = bid * 16 + (tid >> 4);
        int j = tid & 15;
        const float4* wr  = (const float4*)(Wv + (size_t)e * EE);
        const float4* sx4 = (const float4*)sumx;
        float p = 0.f;
#pragma unroll
        for (int jj = 0; jj < 16; ++jj) {
            float4 w = wr[jj * 16 + j], z = sx4[jj * 16 + j];
            p += w.x * z.x + w.y * z.y + w.z * z.z + w.w * z.w;
        }
        p += __shfl_xor(p, 8);
        p += __shfl_xor(p, 4);
        p += __shfl_xor(p, 2);
        p += __shfl_xor(p, 1);
        if (j == 0) bgA[e] = p + (float)SS * bv[e];
        return;
    }
    if (bid < NBG + NVS) {
        int h = bid - NBG;
        float s = 0.f;
        for (int t = wave; t < Lp; t += 4)
            s += vh[((size_t)h * RMAX + t) * DD + lane];
        vp_[wave][lane] = s;
        __syncthreads();
        if (wave == 0)
            vsumh[h * DD + lane] = vp_[0][lane] + vp_[1][lane]
                                 + vp_[2][lane] + vp_[3][lane];
        return;
    }

    int aid = bid - NBG - NVS;
    int gidbase = aid * 4 + wave;
    int pairs = L * HH;
    float* qSw = qS + wave * 64;
    float* wSw = wS + wave * 128;
    for (int wg = gidbase; wg < pairs; wg += NATT * 4) {
        int h = wg & (HH - 1);
        int r = wg >> 4;
        qSw[lane] = qh[((size_t)h * RMAX + r) * DD + lane];
        float s0 = 0.f, s1 = 0.f;
#pragma unroll
        for (int d = 0; d < 64; ++d) {
            float qd = qSw[d];
            const float* kr = kTh + (size_t)(h * DD + d) * RMAX;
            s0 += qd * kr[lane];
            s1 += qd * kr[64 + lane];
        }
        float v0 = (lane < L)      ? s0 : -3.0e38f;
        float v1 = (64 + lane < L) ? s1 : -3.0e38f;
        float m = fmaxf(0.f, fmaxf(v0, v1));
#pragma unroll
        for (int off = 32; off; off >>= 1) m = fmaxf(m, __shfl_xor(m, off));
        float w0 = (lane < L)      ? __expf(s0 - m) : 0.f;
        float w1 = (64 + lane < L) ? __expf(s1 - m) : 0.f;
        float Zl = w0 + w1;
#pragma unroll
        for (int off = 32; off; off >>= 1) Zl += __shfl_xor(Zl, off);
        float em = __expf(-m);
        float Z  = Zl + (float)(SS - L) * em;
        wSw[lane]      = w0;
        wSw[64 + lane] = w1;
        float acc = 0.f;
#pragma unroll 16
        for (int t = 0; t < Lp; ++t)
            acc += wSw[t] * vh[((size_t)h * RMAX + t) * DD + lane];
        float invZ = 1.0f / Z;
        atomicAdd(&betap[h * DD + lane], acc * invZ);
        if (lane == 0) atomicAdd(&alphap[h], em * invZ);
    }
}

// -------- D3: out[e] = bo[e] + Wo[e,:].(beta + alpha o (bgA - vsumh)) / L ----
__global__ __launch_bounds__(256) void d3_kernel(
    const float* __restrict__ Wo, const float* __restrict__ bo,
    const float* __restrict__ ws, float* __restrict__ out) {
    __shared__ float z[EE];
    int tid = threadIdx.x;
    int lane = tid & 63, wave = tid >> 6;
    int L = ((const int*)ws)[1];

    {
        int h = tid >> 4;
        float4 beta = ((const float4*)(ws + OFF_BETA))[tid];
        float  a    = (ws + OFF_ALPHA)[h];
        float4 g    = ((const float4*)(ws + OFF_BGA))[tid];
        float4 vs   = ((const float4*)(ws + OFF_VSUM))[tid];
        ((float4*)z)[tid] = make_float4(beta.x + a * (g.x - vs.x),
                                        beta.y + a * (g.y - vs.y),
                                        beta.z + a * (g.z - vs.z),
                                        beta.w + a * (g.w - vs.w));
    }
    __syncthreads();

    int e = blockIdx.x * 4 + wave;
    const float4* wr = (const float4*)(Wo + (size_t)e * EE);
    const float4* z4 = (const float4*)z;
    float p = 0.f;
#pragma unroll
    for (int it = 0; it < 4; ++it) {
        float4 w = wr[it * 64 + lane], zz = z4[it * 64 + lane];
        p += w.x * zz.x + w.y * zz.y + w.z * zz.z + w.w * zz.w;
    }
#pragma unroll
    for (int off = 32; off; off >>= 1) p += __shfl_xor(p, off);
    if (lane == 0) out[e] = bo[e] + p / (float)L;
}

extern "C" void kernel_launch(void* const* d_in, const int* in_sizes, int n_in,
                              void* d_out, int out_size, void* d_ws, size_t ws_size,
                              hipStream_t stream) {
    const float* x   = (const float*)d_in[0];
    const float* Wq  = (const float*)d_in[1];
    const float* bq  = (const float*)d_in[2];
    const float* Wk  = (const float*)d_in[3];
    const float* bk  = (const float*)d_in[4];
    const float* Wv  = (const float*)d_in[5];
    const float* bv  = (const float*)d_in[6];
    const float* Wo  = (const float*)d_in[7];
    const float* bo  = (const float*)d_in[8];
    const int*   seg = (const int*)d_in[9];
    const int*   pos = (const int*)d_in[10];
    float*       out = (float*)d_out;
    float*       ws  = (float*)d_ws;

    d0_kernel<<<NCOL + 1, 256, 0, stream>>>(x, seg, pos, ws);
    d1_kernel<<<NRED + NPROJ, 256, 0, stream>>>(x, Wq, bq, Wk, bk, Wv, bv, ws);
    d2_kernel<<<NBG + NVS + NATT, 256, 0, stream>>>(Wv, bv, ws);
    d3_kernel<<<EE / 4, 256, 0, stream>>>(Wo, bo, ws, out);
}

// Round 26
// 66.592 us; speedup vs baseline: 3.9738x; 3.9738x over previous
//
#include <hip/hip_runtime.h>
#include <math.h>

#define SS 4096
#define EE 1024
#define HH 16
#define DD 64
#define RMAX 128
#define NCOL 128
#define NTR  8
#define NRED 8
#define NPROJ 1536 // 3 m * 256 e-tiles(4e) * 2 r-tiles; rt in HIGH bit (XCD pairing)
#define NBG 64
#define NVS 16
#define NATT 256

// ---------------------------------------------------------------------------
// REVERT to round-20 configuration (best measured: 65.97us). d1 ledger across
// 12 orthogonal designs (r12-r25): scalar-W 33-42us, LDS-W 39-47us, both-LDS
// 33us, W-registers 233us, K-split 60-80us — floor ~33us = cold-HBM W stream
// at latency-exposed rate; no fp32 structure beats it (no fp32 MFMA on CDNA4).
//   meta   int[0..1]      (s0, L)
//   sumx   [EE]           @64
//   bgA    [EE]           @1088
//   betap  [HH][DD]       @2112   (atomic; zeroed by D1 block 0)
//   alphap [HH]           @3136
//   vsumh  [HH][DD]       @3200
//   partT  [EE][NCOL]     @8192
//   xT     [EE][RMAX]     @139264 (zero-padded rows r>=L)
//   qh     [HH][RMAX][DD] @270336 (rows L..Lp-1 zeroed)
//   kTh    [HH][DD][RMAX] @401408 (cols L..Lp-1 zeroed)
//   vh     [HH][RMAX][DD] @532480 (rows L..Lp-1 zeroed)
// ---------------------------------------------------------------------------
#define OFF_SUMX  64
#define OFF_BGA   1088
#define OFF_BETA  2112
#define OFF_ALPHA 3136
#define OFF_VSUM  3200
#define OFF_PART  8192
#define OFF_XT    (OFF_PART + EE * NCOL)
#define OFF_QH    (OFF_XT + EE * RMAX)
#define OFF_KTH   (OFF_QH + HH * RMAX * DD)
#define OFF_VH    (OFF_KTH + HH * DD * RMAX)

__device__ __forceinline__ void seg_scan(const int* __restrict__ seg,
                                         const int* __restrict__ posp,
                                         int* sh, int& s0, int& L) {
    if (threadIdx.x == 0) { sh[0] = SS; sh[1] = -1; }
    __syncthreads();
    int sid = seg[posp[0]];
    int lmin = SS, lmax = -1;
    for (int i = threadIdx.x; i < SS; i += 256)
        if (seg[i] == sid) { lmin = min(lmin, i); lmax = max(lmax, i); }
#pragma unroll
    for (int off = 32; off; off >>= 1) {
        lmin = min(lmin, __shfl_xor(lmin, off));
        lmax = max(lmax, __shfl_xor(lmax, off));
    }
    if ((threadIdx.x & 63) == 0) { atomicMin(&sh[0], lmin); atomicMax(&sh[1], lmax); }
    __syncthreads();
    s0 = sh[0];
    L  = sh[1] - sh[0] + 1;
    if (L > RMAX) L = RMAX;
    if (L < 1)    L = 1;
}

// -------- D0: colsum -> partT (128 blk) || x-seg transpose -> xT (8 blk) ----
__global__ __launch_bounds__(256) void d0_kernel(
    const float* __restrict__ x, const int* __restrict__ seg,
    const int* __restrict__ posp, float* __restrict__ ws) {
    int bid = blockIdx.x, tid = threadIdx.x;
    if (bid < NCOL) {
        float* partT = ws + OFF_PART;
        int r0 = bid * (SS / NCOL);
        const float4* x4 = (const float4*)x;
        float4 a = make_float4(0.f, 0.f, 0.f, 0.f);
#pragma unroll 8
        for (int r = 0; r < SS / NCOL; ++r) {
            float4 v = x4[(size_t)(r0 + r) * 256 + tid];
            a.x += v.x; a.y += v.y; a.z += v.z; a.w += v.w;
        }
        partT[(size_t)(4 * tid + 0) * NCOL + bid] = a.x;
        partT[(size_t)(4 * tid + 1) * NCOL + bid] = a.y;
        partT[(size_t)(4 * tid + 2) * NCOL + bid] = a.z;
        partT[(size_t)(4 * tid + 3) * NCOL + bid] = a.w;
        return;
    }
    __shared__ float t[128 * 129];
    __shared__ int sh[2];
    int s0, L;
    seg_scan(seg, posp, sh, s0, L);
    int kb = bid - NCOL;
    if (kb == 0 && tid == 0) { ((int*)ws)[0] = s0; ((int*)ws)[1] = L; }
    int k0 = kb * 128;
    float* xT = ws + OFF_XT;
    for (int idx = tid; idx < 128 * 32; idx += 256) {
        int r = idx >> 5, c4 = idx & 31;
        float4 v = make_float4(0.f, 0.f, 0.f, 0.f);
        if (r < L) v = *(const float4*)(x + (size_t)(s0 + r) * EE + k0 + c4 * 4);
        t[r * 129 + c4 * 4 + 0] = v.x;
        t[r * 129 + c4 * 4 + 1] = v.y;
        t[r * 129 + c4 * 4 + 2] = v.z;
        t[r * 129 + c4 * 4 + 3] = v.w;
    }
    __syncthreads();
    for (int idx = tid; idx < 128 * 32; idx += 256) {
        int k = idx >> 5, r4 = idx & 31;
        float4 o;
        o.x = t[(r4 * 4 + 0) * 129 + k];
        o.y = t[(r4 * 4 + 1) * 129 + k];
        o.z = t[(r4 * 4 + 2) * 129 + k];
        o.w = t[(r4 * 4 + 3) * 129 + k];
        *(float4*)(xT + (size_t)(k0 + k) * RMAX + r4 * 4) = o;
    }
}

// -------- D1: sumx reduce + zero accum (8 blk) || QKV projection (1536 blk) --
// r12 structure + rt-high-bit XCD pairing + k-phase stagger (r20).
__global__ __launch_bounds__(256) void d1_kernel(
    const float* __restrict__ Wq, const float* __restrict__ bq,
    const float* __restrict__ Wk, const float* __restrict__ bk,
    const float* __restrict__ Wv, const float* __restrict__ bv,
    float* __restrict__ ws) {
    int bid = blockIdx.x, tid = threadIdx.x;
    if (bid < NRED) {
        if (bid == 0) {   // zero betap+alphap atomic accumulators
            for (int i = tid; i < 1088; i += 256) (ws + OFF_BETA)[i] = 0.f;
        }
        const float* partT = ws + OFF_PART;
        int e  = bid * 128 + (tid >> 1);
        int c0 = (tid & 1) * 64;
        const float4* p4 = (const float4*)(partT + (size_t)e * NCOL + c0);
        float4 s4 = make_float4(0.f, 0.f, 0.f, 0.f);
#pragma unroll
        for (int i = 0; i < 16; ++i) {
            float4 v = p4[i];
            s4.x += v.x; s4.y += v.y; s4.z += v.z; s4.w += v.w;
        }
        float s = s4.x + s4.y + s4.z + s4.w;
        s += __shfl_xor(s, 1);
        if ((tid & 1) == 0) (ws + OFF_SUMX)[e] = s;
        return;
    }
    __shared__ float red[16 * 66];
    int L  = ((const int*)ws)[1];
    int Lp = (L + 63) & ~63;
    int pid = bid - NRED;         // 0..1535
    // rt in HIGH position: blocks p and p+768 share a W slice AND an XCD
    // (768 % 8 == 0 -> same blockIdx%8 -> same XCD; second fetch L2-hits).
    int rt  = (pid >= 768) ? 1 : 0;
    int rem = pid - rt * 768;     // 0..767
    int m   = rem >> 8;           // 0..2
    int eb  = rem & 255;          // 0..255 (4 e each)
    int r0  = rt * 64;
    if (r0 >= Lp) return;
    int e0 = eb * 4;
    const float* W = (m == 0) ? Wq : ((m == 1) ? Wk : Wv);
    const float* b = (m == 0) ? bq : ((m == 1) ? bk : bv);
    int lane = tid & 63;
    int w4 = __builtin_amdgcn_readfirstlane(tid >> 6);   // wave id, uniform
    const float* xcol = ws + OFF_XT + r0 + lane;
    // k-phase stagger: quadrant rotated by block, intra-quadrant offset by
    // block, modular wrap. Pairs (p, p+768) share identical phase (768%4==0,
    // (768>>2)%32==0) so the r19 W-sharing is preserved.
    int kq = ((w4 + pid) & 3) * 256;          // this wave's k quadrant
    int ko = ((pid >> 2) & 31) * 8;           // intra-quadrant start, 8-aligned
    const float* wr0 = W + (size_t)e0 * EE + kq;         // uniform
    float acc0 = 0.f, acc1 = 0.f, acc2 = 0.f, acc3 = 0.f;
    float xv0[8], xv1[8];
#pragma unroll
    for (int u = 0; u < 8; ++u) xv0[u] = xcol[(size_t)(kq + ko + u) * RMAX];
    for (int kk = 0; kk < 256; kk += 16) {
        int kA = (ko + kk) & 255;
        int kB = (ko + kk + 8) & 255;
        int kC = (ko + kk + 16) & 255;        // wraps to ko on last iter (harmless)
        // prefetch second half while first computes
#pragma unroll
        for (int u = 0; u < 8; ++u)
            xv1[u] = xcol[(size_t)(kq + kB + u) * RMAX];
#pragma unroll
        for (int u = 0; u < 8; ++u) {
            float w0 = wr0[0 * EE + kA + u];
            float w1 = wr0[1 * EE + kA + u];
            float w2 = wr0[2 * EE + kA + u];
            float w3 = wr0[3 * EE + kA + u];
            acc0 += xv0[u] * w0; acc1 += xv0[u] * w1;
            acc2 += xv0[u] * w2; acc3 += xv0[u] * w3;
        }
        // prefetch next iteration's first half
#pragma unroll
        for (int u = 0; u < 8; ++u)
            xv0[u] = xcol[(size_t)(kq + kC + u) * RMAX];
#pragma unroll
        for (int u = 0; u < 8; ++u) {
            float w0 = wr0[0 * EE + kB + u];
            float w1 = wr0[1 * EE + kB + u];
            float w2 = wr0[2 * EE + kB + u];
            float w3 = wr0[3 * EE + kB + u];
            acc0 += xv1[u] * w0; acc1 += xv1[u] * w1;
            acc2 += xv1[u] * w2; acc3 += xv1[u] * w3;
        }
    }
    red[(w4 * 4 + 0) * 66 + lane] = acc0;
    red[(w4 * 4 + 1) * 66 + lane] = acc1;
    red[(w4 * 4 + 2) * 66 + lane] = acc2;
    red[(w4 * 4 + 3) * 66 + lane] = acc3;
    __syncthreads();
    int p  = tid >> 6;            // wave -> e index (4 each)
    int rg = r0 + lane;
    float* qh  = ws + OFF_QH;
    float* kTh = ws + OFF_KTH;
    float* vh  = ws + OFF_VH;
    int h = e0 >> 6, d0 = (e0 & 63) + p;
    float v = 0.f;
    if (rg < L)
        v = red[(0 * 4 + p) * 66 + lane] + red[(1 * 4 + p) * 66 + lane]
          + red[(2 * 4 + p) * 66 + lane] + red[(3 * 4 + p) * 66 + lane]
          + b[e0 + p];
    if (m == 1) kTh[(size_t)(h * DD + d0) * RMAX + rg] = v;
    else        ((m == 0) ? qh : vh)[((size_t)h * RMAX + rg) * DD + d0] = v;
}

// -------- D2: bgA (64) || vsumh (16) || attention, 1 wave per (r,h) (256) ----
__global__ __launch_bounds__(256) void d2_kernel(
    const float* __restrict__ Wv, const float* __restrict__ bv,
    float* __restrict__ ws) {
    __shared__ float qS[4 * 64];
    __shared__ float wS[4 * 128];
    __shared__ float vp_[4][64];
    const float* sumx = ws + OFF_SUMX;
    float* bgA    = ws + OFF_BGA;
    float* betap  = ws + OFF_BETA;
    float* alphap = ws + OFF_ALPHA;
    float* vsumh  = ws + OFF_VSUM;
    const float* qh  = ws + OFF_QH;
    const float* kTh = ws + OFF_KTH;
    const float* vh  = ws + OFF_VH;

    int bid = blockIdx.x, tid = threadIdx.x;
    int lane = tid & 63, wave = tid >> 6;
    int L  = ((const int*)ws)[1];
    int Lp = (L + 63) & ~63;

    if (bid < NBG) {
        int e = bid * 16 + (tid >> 4);
        int j = tid & 15;
        const float4* wr  = (const float4*)(Wv + (size_t)e * EE);
        const float4* sx4 = (const float4*)sumx;
        float p = 0.f;
#pragma unroll
        for (int jj = 0; jj < 16; ++jj) {
            float4 w = wr[jj * 16 + j], z = sx4[jj * 16 + j];
            p += w.x * z.x + w.y * z.y + w.z * z.z + w.w * z.w;
        }
        p += __shfl_xor(p, 8);
        p += __shfl_xor(p, 4);
        p += __shfl_xor(p, 2);
        p += __shfl_xor(p, 1);
        if (j == 0) bgA[e] = p + (float)SS * bv[e];
        return;
    }
    if (bid < NBG + NVS) {
        int h = bid - NBG;
        float s = 0.f;
        for (int t = wave; t < Lp; t += 4)
            s += vh[((size_t)h * RMAX + t) * DD + lane];
        vp_[wave][lane] = s;
        __syncthreads();
        if (wave == 0)
            vsumh[h * DD + lane] = vp_[0][lane] + vp_[1][lane]
                                 + vp_[2][lane] + vp_[3][lane];
        return;
    }

    int aid = bid - NBG - NVS;
    int gidbase = aid * 4 + wave;
    int pairs = L * HH;
    float* qSw = qS + wave * 64;
    float* wSw = wS + wave * 128;
    for (int wg = gidbase; wg < pairs; wg += NATT * 4) {
        int h = wg & (HH - 1);
        int r = wg >> 4;
        qSw[lane] = qh[((size_t)h * RMAX + r) * DD + lane];
        float s0 = 0.f, s1 = 0.f;
#pragma unroll
        for (int d = 0; d < 64; ++d) {
            float qd = qSw[d];
            const float* kr = kTh + (size_t)(h * DD + d) * RMAX;
            s0 += qd * kr[lane];
            s1 += qd * kr[64 + lane];
        }
        float v0 = (lane < L)      ? s0 : -3.0e38f;
        float v1 = (64 + lane < L) ? s1 : -3.0e38f;
        float m = fmaxf(0.f, fmaxf(v0, v1));
#pragma unroll
        for (int off = 32; off; off >>= 1) m = fmaxf(m, __shfl_xor(m, off));
        float w0 = (lane < L)      ? __expf(s0 - m) : 0.f;
        float w1 = (64 + lane < L) ? __expf(s1 - m) : 0.f;
        float Zl = w0 + w1;
#pragma unroll
        for (int off = 32; off; off >>= 1) Zl += __shfl_xor(Zl, off);
        float em = __expf(-m);
        float Z  = Zl + (float)(SS - L) * em;
        wSw[lane]      = w0;
        wSw[64 + lane] = w1;
        float acc = 0.f;
#pragma unroll 16
        for (int t = 0; t < Lp; ++t)
            acc += wSw[t] * vh[((size_t)h * RMAX + t) * DD + lane];
        float invZ = 1.0f / Z;
        atomicAdd(&betap[h * DD + lane], acc * invZ);
        if (lane == 0) atomicAdd(&alphap[h], em * invZ);
    }
}

// -------- D3: out[e] = bo[e] + Wo[e,:].(beta + alpha o (bgA - vsumh)) / L ----
__global__ __launch_bounds__(256) void d3_kernel(
    const float* __restrict__ Wo, const float* __restrict__ bo,
    const float* __restrict__ ws, float* __restrict__ out) {
    __shared__ float z[EE];
    int tid = threadIdx.x;
    int lane = tid & 63, wave = tid >> 6;
    int L = ((const int*)ws)[1];

    {
        int h = tid >> 4;
        float4 beta = ((const float4*)(ws + OFF_BETA))[tid];
        float  a    = (ws + OFF_ALPHA)[h];
        float4 g    = ((const float4*)(ws + OFF_BGA))[tid];
        float4 vs   = ((const float4*)(ws + OFF_VSUM))[tid];
        ((float4*)z)[tid] = make_float4(beta.x + a * (g.x - vs.x),
                                        beta.y + a * (g.y - vs.y),
                                        beta.z + a * (g.z - vs.z),
                                        beta.w + a * (g.w - vs.w));
    }
    __syncthreads();

    int e = blockIdx.x * 4 + wave;
    const float4* wr = (const float4*)(Wo + (size_t)e * EE);
    const float4* z4 = (const float4*)z;
    float p = 0.f;
#pragma unroll
    for (int it = 0; it < 4; ++it) {
        float4 w = wr[it * 64 + lane], zz = z4[it * 64 + lane];
        p += w.x * zz.x + w.y * zz.y + w.z * zz.z + w.w * zz.w;
    }
#pragma unroll
    for (int off = 32; off; off >>= 1) p += __shfl_xor(p, off);
    if (lane == 0) out[e] = bo[e] + p / (float)L;
}

extern "C" void kernel_launch(void* const* d_in, const int* in_sizes, int n_in,
                              void* d_out, int out_size, void* d_ws, size_t ws_size,
                              hipStream_t stream) {
    const float* x   = (const float*)d_in[0];
    const float* Wq  = (const float*)d_in[1];
    const float* bq  = (const float*)d_in[2];
    const float* Wk  = (const float*)d_in[3];
    const float* bk  = (const float*)d_in[4];
    const float* Wv  = (const float*)d_in[5];
    const float* bv  = (const float*)d_in[6];
    const float* Wo  = (const float*)d_in[7];
    const float* bo  = (const float*)d_in[8];
    const int*   seg = (const int*)d_in[9];
    const int*   pos = (const int*)d_in[10];
    float*       out = (float*)d_out;
    float*       ws  = (float*)d_ws;

    d0_kernel<<<NCOL + NTR, 256, 0, stream>>>(x, seg, pos, ws);
    d1_kernel<<<NRED + NPROJ, 256, 0, stream>>>(Wq, bq, Wk, bk, Wv, bv, ws);
    d2_kernel<<<NBG + NVS + NATT, 256, 0, stream>>>(Wv, bv, ws);
    d3_kernel<<<EE / 4, 256, 0, stream>>>(Wo, bo, ws, out);
}